// Round 9
// baseline (712.947 us; speedup 1.0000x reference)
//
#include <hip/hip_runtime.h>
#include <hip/hip_fp16.h>

#define NP 200000
#define NA 100000
#define NE 1200000
#define NTOT (NA + NP)

// partitioned CSR build geometry
#define CHUNK 4096              // edges per partition block (16/thread)
#define NCHUNK 586              // ceil(2*NE / CHUNK)
#define NBUCKA 98               // ceil(NA/1024)
#define NBUCKP 196              // ceil(NP/1024)
#define NBUCK (NBUCKA + NBUCKP) // 294
#define MATN (NBUCK * NCHUNK)   // 172284

typedef _Float16 half8 __attribute__((ext_vector_type(8)));
typedef float f32x4 __attribute__((ext_vector_type(4)));

// ---------------- scans (exclusive) ----------------

__global__ __launch_bounds__(256) void scan1_k(const int* __restrict__ in, int* __restrict__ out,
                                               int* __restrict__ bsums, int n) {
    __shared__ int lds[256];
    int t = threadIdx.x;
    int base = blockIdx.x * 1024 + t * 4;
    int v0 = (base + 0 < n) ? in[base + 0] : 0;
    int v1 = (base + 1 < n) ? in[base + 1] : 0;
    int v2 = (base + 2 < n) ? in[base + 2] : 0;
    int v3 = (base + 3 < n) ? in[base + 3] : 0;
    lds[t] = v0 + v1 + v2 + v3;
    __syncthreads();
    for (int off = 1; off < 256; off <<= 1) {
        int x = (t >= off) ? lds[t - off] : 0;
        __syncthreads();
        lds[t] += x;
        __syncthreads();
    }
    if (t == 255) bsums[blockIdx.x] = lds[255];
    int run = (t == 0) ? 0 : lds[t - 1];
    if (base + 0 < n) out[base + 0] = run; run += v0;
    if (base + 1 < n) out[base + 1] = run; run += v1;
    if (base + 2 < n) out[base + 2] = run; run += v2;
    if (base + 3 < n) out[base + 3] = run;
}

__global__ __launch_bounds__(1024) void scan2_k(int* bsums, int nb) {  // nb <= 1024, single block
    __shared__ int lds[1024];
    int t = threadIdx.x;
    int v = (t < nb) ? bsums[t] : 0;
    lds[t] = v;
    __syncthreads();
    for (int off = 1; off < 1024; off <<= 1) {
        int x = (t >= off) ? lds[t - off] : 0;
        __syncthreads();
        lds[t] += x;
        __syncthreads();
    }
    if (t < nb) bsums[t] = lds[t] - v;  // exclusive
}

__global__ __launch_bounds__(256) void scan3_k(int* __restrict__ out, const int* __restrict__ bsums, int n) {
    int add = bsums[blockIdx.x];
    int base = blockIdx.x * 1024 + threadIdx.x * 4;
#pragma unroll
    for (int j = 0; j < 4; j++)
        if (base + j < n) out[base + j] += add;
}

// ---------------- partitioned CSR build ----------------

__device__ __forceinline__ int bucket_gbase(int b) {
    return (b < NBUCKA) ? (b << 10) : NA + ((b - NBUCKA) << 10);
}
__device__ __forceinline__ int bucket_nrows(int b) {
    return (b < NBUCKA) ? min(1024, NA - (b << 10)) : min(1024, NP - ((b - NBUCKA) << 10));
}

__global__ __launch_bounds__(256) void part_cnt_k(const int* __restrict__ pa_row, const int* __restrict__ ap_row,
                                                  int* __restrict__ mat) {
    __shared__ int lh[NBUCK];
    int t = threadIdx.x, c = blockIdx.x;
    for (int b = t; b < NBUCK; b += 256) lh[b] = 0;
    __syncthreads();
    int base = c * CHUNK;
#pragma unroll
    for (int k = 0; k < CHUNK / 256; k++) {
        int i = base + k * 256 + t;
        if (i < 2 * NE) {
            int b = (i < NE) ? (pa_row[i] >> 10) : (NBUCKA + (ap_row[i - NE] >> 10));
            atomicAdd(&lh[b], 1);
        }
    }
    __syncthreads();
    for (int b = t; b < NBUCK; b += 256) mat[b * NCHUNK + c] = lh[b];
}

// record: x = (rowlocal<<20) | col, y = val bits
__global__ __launch_bounds__(256) void part_scat_k(const int* __restrict__ pa_row, const int* __restrict__ pa_col,
                                                   const float* __restrict__ pa_val,
                                                   const int* __restrict__ ap_row, const int* __restrict__ ap_col,
                                                   const float* __restrict__ ap_val,
                                                   const int* __restrict__ matoff, int2* __restrict__ staged) {
    __shared__ int lc[NBUCK];
    int t = threadIdx.x, c = blockIdx.x;
    for (int b = t; b < NBUCK; b += 256) lc[b] = 0;
    __syncthreads();
    int base = c * CHUNK;
#pragma unroll
    for (int k = 0; k < CHUNK / 256; k++) {
        int i = base + k * 256 + t;
        if (i < 2 * NE) {
            int b, rl, col; float v;
            if (i < NE) {
                int r = pa_row[i];
                b = r >> 10; rl = r & 1023; col = pa_col[i]; v = pa_val[i];
            } else {
                int r = ap_row[i - NE];
                b = NBUCKA + (r >> 10); rl = r & 1023; col = ap_col[i - NE]; v = ap_val[i - NE];
            }
            int rk = atomicAdd(&lc[b], 1);  // LDS rank within (block,bucket)
            staged[matoff[b * NCHUNK + c] + rk] = make_int2((rl << 20) | col, __float_as_int(v));
        }
    }
}

__global__ __launch_bounds__(256) void bcnt_k(const int2* __restrict__ staged, const int* __restrict__ matoff,
                                              int* __restrict__ cnt_all) {
    __shared__ int lcnt[1024];
    int t = threadIdx.x, b = blockIdx.x;
    for (int r = t; r < 1024; r += 256) lcnt[r] = 0;
    __syncthreads();
    int s = matoff[b * NCHUNK];
    int e = (b + 1 < NBUCK) ? matoff[(b + 1) * NCHUNK] : 2 * NE;
    for (int i = s + t; i < e; i += 256) atomicAdd(&lcnt[staged[i].x >> 20], 1);
    __syncthreads();
    int gb = bucket_gbase(b), nr = bucket_nrows(b);
    for (int r = t; r < nr; r += 256) cnt_all[gb + r] = lcnt[r];
}

__global__ __launch_bounds__(256) void place_k(const int2* __restrict__ staged, const int* __restrict__ matoff,
                                               const int* __restrict__ off_all, int2* __restrict__ csr_all) {
    __shared__ int lcur[1024];
    int t = threadIdx.x, b = blockIdx.x;
    for (int r = t; r < 1024; r += 256) lcur[r] = 0;
    __syncthreads();
    int s = matoff[b * NCHUNK];
    int e = (b + 1 < NBUCK) ? matoff[(b + 1) * NCHUNK] : 2 * NE;
    int gb = bucket_gbase(b);
    for (int i = s + t; i < e; i += 256) {
        int2 rec = staged[i];
        int rl = rec.x >> 20;
        int pos = off_all[gb + rl] + atomicAdd(&lcur[rl], 1);
        csr_all[pos] = make_int2(rec.x & 0xFFFFF, rec.y);
    }
}

// ---------------- SpMM gather, fp16 z-table (unchanged) ----------------

__device__ __forceinline__ void fma_h8(float acc[8], float v, uint4 r) {
    __half2 h0 = *(__half2*)&r.x;
    __half2 h1 = *(__half2*)&r.y;
    __half2 h2 = *(__half2*)&r.z;
    __half2 h3 = *(__half2*)&r.w;
    float2 f0 = __half22float2(h0);
    float2 f1 = __half22float2(h1);
    float2 f2 = __half22float2(h2);
    float2 f3 = __half22float2(h3);
    acc[0] = fmaf(v, f0.x, acc[0]);
    acc[1] = fmaf(v, f0.y, acc[1]);
    acc[2] = fmaf(v, f1.x, acc[2]);
    acc[3] = fmaf(v, f1.y, acc[3]);
    acc[4] = fmaf(v, f2.x, acc[4]);
    acc[5] = fmaf(v, f2.y, acc[5]);
    acc[6] = fmaf(v, f3.x, acc[6]);
    acc[7] = fmaf(v, f3.y, acc[7]);
}

__device__ __forceinline__ void store_h8(uint4* out16, int g, int l, const float acc[8]) {
    __half2 p0 = __floats2half2_rn(acc[0], acc[1]);
    __half2 p1 = __floats2half2_rn(acc[2], acc[3]);
    __half2 p2 = __floats2half2_rn(acc[4], acc[5]);
    __half2 p3 = __floats2half2_rn(acc[6], acc[7]);
    uint4 o;
    o.x = *(unsigned*)&p0;
    o.y = *(unsigned*)&p1;
    o.z = *(unsigned*)&p2;
    o.w = *(unsigned*)&p3;
    out16[(size_t)g * 8 + l] = o;
}

__device__ __forceinline__ void store_f8(float4* out32, int g, int l, const float acc[8]) {
    out32[(size_t)g * 16 + l * 2 + 0] = make_float4(acc[0], acc[1], acc[2], acc[3]);
    out32[(size_t)g * 16 + l * 2 + 1] = make_float4(acc[4], acc[5], acc[6], acc[7]);
}

__global__ __launch_bounds__(256) void spmm_k(const int2* __restrict__ csr, const int* __restrict__ off,
                                              const int* __restrict__ cnt, const uint4* __restrict__ z,
                                              float4* __restrict__ out32, uint4* __restrict__ out16,
                                              int nrows) {
    int g = blockIdx.x * 32 + (threadIdx.x >> 3);
    int l = threadIdx.x & 7;
    if (g >= nrows) return;
    int start = off[g], deg = cnt[g];
    float acc[8];
#pragma unroll
    for (int i = 0; i < 8; i++) acc[i] = 0.f;

    if (deg > 0) {
        int2 e[8];
#pragma unroll
        for (int k = 0; k < 8; k++) e[k] = csr[start + min(k, deg - 1)];
        for (int j = 0; j < deg; j += 8) {
            uint4 r[8];
#pragma unroll
            for (int k = 0; k < 8; k++) r[k] = z[e[k].x * 8 + l];
            float v[8];
#pragma unroll
            for (int k = 0; k < 8; k++) v[k] = (j + k < deg) ? __int_as_float(e[k].y) : 0.f;
            int2 en[8];
            bool more = (j + 8) < deg;
            if (more) {
#pragma unroll
                for (int k = 0; k < 8; k++) en[k] = csr[start + min(j + 8 + k, deg - 1)];
            }
#pragma unroll
            for (int k = 0; k < 8; k++) fma_h8(acc, v[k], r[k]);
            if (more) {
#pragma unroll
                for (int k = 0; k < 8; k++) e[k] = en[k];
            }
        }
    }
    if (out32) store_f8(out32, g, l, acc);
    if (out16) store_h8(out16, g, l, acc);
}

__global__ __launch_bounds__(256) void spmm2_k(const int2* __restrict__ csr, const int* __restrict__ off,
                                               const int* __restrict__ cnt,
                                               const uint4* __restrict__ zA, const uint4* __restrict__ zB,
                                               float4* __restrict__ outA32, uint4* __restrict__ outA16,
                                               float4* __restrict__ outB32, uint4* __restrict__ outB16,
                                               int nrows) {
    int g = blockIdx.x * 32 + (threadIdx.x >> 3);
    int l = threadIdx.x & 7;
    if (g >= nrows) return;
    int start = off[g], deg = cnt[g];
    float accA[8], accB[8];
#pragma unroll
    for (int i = 0; i < 8; i++) { accA[i] = 0.f; accB[i] = 0.f; }

    if (deg > 0) {
        int2 e[8];
#pragma unroll
        for (int k = 0; k < 8; k++) e[k] = csr[start + min(k, deg - 1)];
        for (int j = 0; j < deg; j += 8) {
            uint4 rA[8], rB[8];
#pragma unroll
            for (int k = 0; k < 8; k++) {
                int idx = e[k].x * 8 + l;
                rA[k] = zA[idx];
                rB[k] = zB[idx];
            }
            float v[8];
#pragma unroll
            for (int k = 0; k < 8; k++) v[k] = (j + k < deg) ? __int_as_float(e[k].y) : 0.f;
            int2 en[8];
            bool more = (j + 8) < deg;
            if (more) {
#pragma unroll
                for (int k = 0; k < 8; k++) en[k] = csr[start + min(j + 8 + k, deg - 1)];
            }
#pragma unroll
            for (int k = 0; k < 8; k++) {
                fma_h8(accA, v[k], rA[k]);
                fma_h8(accB, v[k], rB[k]);
            }
            if (more) {
#pragma unroll
                for (int k = 0; k < 8; k++) e[k] = en[k];
            }
        }
    }
    if (outA32) store_f8(outA32, g, l, accA);
    if (outA16) store_h8(outA16, g, l, accA);
    if (outB32) store_f8(outB32, g, l, accB);
    if (outB16) store_h8(outB16, g, l, accB);
}

// ---------------- dense projection via fp16 MFMA ----------------
// Templated on K; per-lane full x-row fragment preloaded into registers
// (K/16 float4 loads issued back-to-back -> 128-256 B/lane in flight),
// then fully-unrolled convert+MFMA chain against L1-resident wt.

__global__ __launch_bounds__(256) void wconv_k(const float* __restrict__ Wp, const float* __restrict__ Wa,
                                               __half* __restrict__ wtP, __half* __restrict__ wtA) {
    int i = blockIdx.x * 256 + threadIdx.x;
    int stride = gridDim.x * 256;
    for (int idx = i; idx < 64 * 256; idx += stride) {
        int c = idx >> 8, k = idx & 255;
        wtP[idx] = (__half)Wp[k * 64 + c];
    }
    for (int idx = i; idx < 64 * 128; idx += stride) {
        int c = idx >> 7, k = idx & 127;
        wtA[idx] = (__half)Wa[k * 64 + c];
    }
}

template <int K>
__global__ __launch_bounds__(256) void gemm2_k(const float* __restrict__ x, const __half* __restrict__ wt,
                                               __half* __restrict__ z, int nrows) {
    int w = threadIdx.x >> 6;   // wave 0..3
    int l = threadIdx.x & 63;
    int r0 = blockIdx.x * 64;
    int arow = r0 + w * 16 + (l & 15);
    int kq = (l >> 4) * 8;

    // preload entire per-lane x fragment (all K/32 k-steps x 2 float4)
    float4 xf[K / 16];
    bool valid = arow < nrows;
    const float* xp = x + (size_t)arow * K + kq;
#pragma unroll
    for (int q = 0; q < K / 32; q++) {
        xf[2 * q + 0] = valid ? *(const float4*)(xp + q * 32 + 0) : make_float4(0.f, 0.f, 0.f, 0.f);
        xf[2 * q + 1] = valid ? *(const float4*)(xp + q * 32 + 4) : make_float4(0.f, 0.f, 0.f, 0.f);
    }

    f32x4 acc0 = {0.f, 0.f, 0.f, 0.f};
    f32x4 acc1 = {0.f, 0.f, 0.f, 0.f};
    f32x4 acc2 = {0.f, 0.f, 0.f, 0.f};
    f32x4 acc3 = {0.f, 0.f, 0.f, 0.f};

    const __half* wb = wt + (size_t)(l & 15) * K + kq;
#pragma unroll
    for (int q = 0; q < K / 32; q++) {
        half8 a;
        float4 f0 = xf[2 * q + 0], f1 = xf[2 * q + 1];
        a[0] = (_Float16)f0.x; a[1] = (_Float16)f0.y;
        a[2] = (_Float16)f0.z; a[3] = (_Float16)f0.w;
        a[4] = (_Float16)f1.x; a[5] = (_Float16)f1.y;
        a[6] = (_Float16)f1.z; a[7] = (_Float16)f1.w;
        half8 b0 = *(const half8*)(wb + q * 32);
        half8 b1 = *(const half8*)(wb + q * 32 + (size_t)16 * K);
        half8 b2 = *(const half8*)(wb + q * 32 + (size_t)32 * K);
        half8 b3 = *(const half8*)(wb + q * 32 + (size_t)48 * K);
        acc0 = __builtin_amdgcn_mfma_f32_16x16x32_f16(a, b0, acc0, 0, 0, 0);
        acc1 = __builtin_amdgcn_mfma_f32_16x16x32_f16(a, b1, acc1, 0, 0, 0);
        acc2 = __builtin_amdgcn_mfma_f32_16x16x32_f16(a, b2, acc2, 0, 0, 0);
        acc3 = __builtin_amdgcn_mfma_f32_16x16x32_f16(a, b3, acc3, 0, 0, 0);
    }

    int orow0 = r0 + w * 16 + (l >> 4) * 4;
    int col = l & 15;
#pragma unroll
    for (int i = 0; i < 4; i++) {
        int r = orow0 + i;
        if (r < nrows) {
            __half* zr = z + (size_t)r * 64;
            zr[col +  0] = (__half)acc0[i];
            zr[col + 16] = (__half)acc1[i];
            zr[col + 32] = (__half)acc2[i];
            zr[col + 48] = (__half)acc3[i];
        }
    }
}

// ---------------- launch ----------------

extern "C" void kernel_launch(void* const* d_in, const int* in_sizes, int n_in,
                              void* d_out, int out_size, void* d_ws, size_t ws_size,
                              hipStream_t stream) {
    const float* x_paper  = (const float*)d_in[0];
    const float* x_author = (const float*)d_in[1];
    const float* W_paper  = (const float*)d_in[2];
    const float* W_author = (const float*)d_in[3];
    const int*   pa_row   = (const int*)d_in[4];
    const int*   pa_col   = (const int*)d_in[5];
    const float* pa_val   = (const float*)d_in[6];
    const int*   ap_row   = (const int*)d_in[7];
    const int*   ap_col   = (const int*)d_in[8];
    const float* ap_val   = (const float*)d_in[9];

    char* ws = (char*)d_ws;
    size_t o = 0;
    auto alloc = [&](size_t bytes) -> char* {
        char* p = ws + o;
        o += (bytes + 255) & ~(size_t)255;
        return p;
    };
    __half* zp16  = (__half*)alloc((size_t)NP * 64 * 2);  // zp, later reused as g
    __half* za16  = (__half*)alloc((size_t)NA * 64 * 2);
    __half* h16   = (__half*)alloc((size_t)NA * 64 * 2);  // h, later h2
    __half* pap16 = (__half*)alloc((size_t)NP * 64 * 2);
    int2*  csr_all = (int2*)alloc((size_t)2 * NE * 8);
    int2*  staged  = (int2*)alloc((size_t)2 * NE * 8);
    int* mat     = (int*)alloc((size_t)MATN * 4);
    int* matoff  = (int*)alloc((size_t)MATN * 4);
    int* cnt_all = (int*)alloc(NTOT * 4);
    int* off_all = (int*)alloc(NTOT * 4);
    int* bsums   = (int*)alloc(1024 * 4);
    __half* wtP  = (__half*)alloc(64 * 256 * 2);
    __half* wtA  = (__half*)alloc(64 * 128 * 2);

    float* out_pap   = (float*)d_out;
    float* out_papap = out_pap + (size_t)NP * 64;
    float* out_apa   = out_papap + (size_t)NP * 64;

    const int nb_mat = (MATN + 1023) / 1024;  // 169
    const int nb_tot = (NTOT + 1023) / 1024;  // 293

    // ---- partitioned CSR build (no global atomics, no memsets) ----
    part_cnt_k<<<NCHUNK, 256, 0, stream>>>(pa_row, ap_row, mat);
    scan1_k<<<nb_mat, 256, 0, stream>>>(mat, matoff, bsums, MATN);
    scan2_k<<<1, 1024, 0, stream>>>(bsums, nb_mat);
    scan3_k<<<nb_mat, 256, 0, stream>>>(matoff, bsums, MATN);
    part_scat_k<<<NCHUNK, 256, 0, stream>>>(pa_row, pa_col, pa_val, ap_row, ap_col, ap_val,
                                            matoff, staged);
    bcnt_k<<<NBUCK, 256, 0, stream>>>(staged, matoff, cnt_all);
    scan1_k<<<nb_tot, 256, 0, stream>>>(cnt_all, off_all, bsums, NTOT);
    scan2_k<<<1, 1024, 0, stream>>>(bsums, nb_tot);
    scan3_k<<<nb_tot, 256, 0, stream>>>(off_all, bsums, NTOT);
    place_k<<<NBUCK, 256, 0, stream>>>(staged, matoff, off_all, csr_all);

    // ---- projections (fp16 MFMA, register-preloaded x) ----
    wconv_k<<<64, 256, 0, stream>>>(W_paper, W_author, wtP, wtA);
    gemm2_k<256><<<(NP + 63) / 64, 256, 0, stream>>>(x_paper, wtP, zp16, NP);
    gemm2_k<128><<<(NA + 63) / 64, 256, 0, stream>>>(x_author, wtA, za16, NA);

    const int* off_pa = off_all;        // author rows
    const int* cnt_pa = cnt_all;
    const int* off_ap = off_all + NA;   // paper rows
    const int* cnt_ap = cnt_all + NA;

    // pass 1: h = pa@zp (fp16)
    spmm_k<<<NA / 32, 256, 0, stream>>>(csr_all, off_pa, cnt_pa, (const uint4*)zp16,
                                        nullptr, (uint4*)h16, NA);
    // pass 2 (fused over ap): pap = ap@h (fp32 + fp16) ; g = ap@za (fp16, reuse zp16)
    spmm2_k<<<NP / 32, 256, 0, stream>>>(csr_all, off_ap, cnt_ap,
                                         (const uint4*)h16, (const uint4*)za16,
                                         (float4*)out_pap, (uint4*)pap16,
                                         nullptr, (uint4*)zp16, NP);
    // pass 3 (fused over pa): h2 = pa@pap (fp16, reuse h16) ; apa = pa@g (fp32)
    spmm2_k<<<NA / 32, 256, 0, stream>>>(csr_all, off_pa, cnt_pa,
                                         (const uint4*)pap16, (const uint4*)zp16,
                                         nullptr, (uint4*)h16,
                                         (float4*)out_apa, nullptr, NA);
    // pass 4: papap = ap@h2 (fp32)
    spmm_k<<<NP / 32, 256, 0, stream>>>(csr_all, off_ap, cnt_ap, (const uint4*)h16,
                                        (float4*)out_papap, nullptr, NP);
}